// Round 2
// baseline (317.140 us; speedup 1.0000x reference)
//
#include <hip/hip_runtime.h>
#include <cstdint>
#include <cstddef>

// dist[m][n] = ||a_m||^2 + ||b_n||^2 - 2 a_m.b_n ; M=100000, N=2048, K=64, f32.
// Cross term via bf16 MFMA 16x16x32 with operands SWAPPED (mfma(b, a)) so each
// lane's 4 acc elements are 4 consecutive output columns of one row -> float4
// nontemporal stores. -2 is folded into the bf16 B copy (exact scaling).

typedef __bf16 v8bf __attribute__((ext_vector_type(8)));
typedef float  v4f  __attribute__((ext_vector_type(4)));

__device__ inline unsigned short f32_to_bf16_rne(float f) {
    union { float f; uint32_t u; } c; c.f = f;
    uint32_t u = c.u;
    uint32_t r = (u + 0x7fffu + ((u >> 16) & 1u)) >> 16;   // round-to-nearest-even
    return (unsigned short)r;
}

// mat_2 (N x 64 f32) -> Bbf = bf16(-2*b) in ws; sq2[n] = ||b_n||^2 (f32, exact).
__global__ __launch_bounds__(256) void prep_kernel(const float* __restrict__ B,
                                                   unsigned short* __restrict__ Bbf,
                                                   float* __restrict__ sq2, int N) {
    int t = blockIdx.x * 256 + threadIdx.x;   // 4 threads per row, 16 elems each
    int row = t >> 2;
    if (row >= N) return;
    int q = (t & 3) * 16;
    const float* src = B + (size_t)row * 64 + q;
    unsigned short* dst = Bbf + (size_t)row * 64 + q;
    float s = 0.f;
#pragma unroll
    for (int i = 0; i < 4; ++i) {
        float4 v = *reinterpret_cast<const float4*>(src + 4 * i);
        s += v.x * v.x + v.y * v.y + v.z * v.z + v.w * v.w;
        uint2 p;
        p.x = (uint32_t)f32_to_bf16_rne(-2.f * v.x) | ((uint32_t)f32_to_bf16_rne(-2.f * v.y) << 16);
        p.y = (uint32_t)f32_to_bf16_rne(-2.f * v.z) | ((uint32_t)f32_to_bf16_rne(-2.f * v.w) << 16);
        *reinterpret_cast<uint2*>(dst + 4 * i) = p;
    }
    s += __shfl_xor(s, 1);
    s += __shfl_xor(s, 2);
    if ((t & 3) == 0) sq2[row] = s;
}

// Block: 256 threads = 4 waves (2 row-halves x 2 col-halves). Block tile:
// 64 rows x N (chunks of 128 cols; each wave does 32 rows x 64 cols / chunk).
__global__ __launch_bounds__(256) void dist_kernel(const float* __restrict__ A,
                                                   const unsigned short* __restrict__ Bbf,
                                                   const float* __restrict__ sq2,
                                                   float* __restrict__ out,
                                                   int M, int N) {
    __shared__ alignas(16) unsigned short a_lds[64][72];   // +8 pad: conflict-free b128 reads
    __shared__ float sq1_lds[64];

    const int t  = threadIdx.x;
    const int m0 = blockIdx.x * 64;

    // ---- stage A tile (f32 -> bf16) + row norms ----
    {
        int r = t >> 2;
        int q = (t & 3) * 16;
        int m = m0 + r; if (m >= M) m = M - 1;   // clamp tail rows (stores predicated later)
        const float* src = A + (size_t)m * 64 + q;
        float s = 0.f;
#pragma unroll
        for (int i = 0; i < 4; ++i) {
            float4 v = *reinterpret_cast<const float4*>(src + 4 * i);
            s += v.x * v.x + v.y * v.y + v.z * v.z + v.w * v.w;
            uint2 p;
            p.x = (uint32_t)f32_to_bf16_rne(v.x) | ((uint32_t)f32_to_bf16_rne(v.y) << 16);
            p.y = (uint32_t)f32_to_bf16_rne(v.z) | ((uint32_t)f32_to_bf16_rne(v.w) << 16);
            *reinterpret_cast<uint2*>(&a_lds[r][q + 4 * i]) = p;
        }
        s += __shfl_xor(s, 1);
        s += __shfl_xor(s, 2);
        if ((t & 3) == 0) sq1_lds[r] = s;
    }
    __syncthreads();

    const int lane = t & 63;
    const int w    = t >> 6;
    const int wm   = w >> 1;      // row half
    const int wn   = w & 1;       // col half within 128-chunk
    const int lg   = lane >> 4;
    const int li   = lane & 15;

    // A fragments (MFMA 2nd operand): lane li = a-row-in-tile. Held all kernel.
    v8bf af[2][2];
#pragma unroll
    for (int rt = 0; rt < 2; ++rt)
#pragma unroll
        for (int kb = 0; kb < 2; ++kb)
            af[rt][kb] = *reinterpret_cast<const v8bf*>(&a_lds[32 * wm + 16 * rt + li][kb * 32 + 8 * lg]);

    float s1[2];
    int   row[2];
    float* orow[2];
#pragma unroll
    for (int rt = 0; rt < 2; ++rt) {
        row[rt]  = m0 + 32 * wm + 16 * rt + li;
        s1[rt]   = sq1_lds[32 * wm + 16 * rt + li];
        orow[rt] = out + (size_t)row[rt] * N;
    }
    const bool full = (m0 + 64 <= M);

    auto loadb = [&](v8bf (&bf)[4][2], int ncol) {
#pragma unroll
        for (int ct = 0; ct < 4; ++ct)
#pragma unroll
            for (int kb = 0; kb < 2; ++kb)
                bf[ct][kb] = *reinterpret_cast<const v8bf*>(
                    &Bbf[(size_t)(ncol + 16 * ct + li) * 64 + kb * 32 + 8 * lg]);
    };

    auto body = [&](const v8bf (&bf)[4][2], int ncol) {
        float4 s2v[4];
#pragma unroll
        for (int ct = 0; ct < 4; ++ct)
            s2v[ct] = *reinterpret_cast<const float4*>(&sq2[ncol + 16 * ct + 4 * lg]);
        v4f acc[2][4];
#pragma unroll
        for (int rt = 0; rt < 2; ++rt)
#pragma unroll
            for (int ct = 0; ct < 4; ++ct) {
                acc[rt][ct][0] = s1[rt] + s2v[ct].x;
                acc[rt][ct][1] = s1[rt] + s2v[ct].y;
                acc[rt][ct][2] = s1[rt] + s2v[ct].z;
                acc[rt][ct][3] = s1[rt] + s2v[ct].w;
            }
#pragma unroll
        for (int rt = 0; rt < 2; ++rt)
#pragma unroll
            for (int ct = 0; ct < 4; ++ct) {
                acc[rt][ct] = __builtin_amdgcn_mfma_f32_16x16x32_bf16(bf[ct][0], af[rt][0], acc[rt][ct], 0, 0, 0);
                acc[rt][ct] = __builtin_amdgcn_mfma_f32_16x16x32_bf16(bf[ct][1], af[rt][1], acc[rt][ct], 0, 0, 0);
            }
        // D mapping after swap: lane li = a-row, regs j = 4 consecutive b-cols.
        if (full) {
#pragma unroll
            for (int rt = 0; rt < 2; ++rt)
#pragma unroll
                for (int ct = 0; ct < 4; ++ct)
                    __builtin_nontemporal_store(acc[rt][ct],
                        reinterpret_cast<v4f*>(orow[rt] + ncol + 16 * ct + 4 * lg));
        } else {
#pragma unroll
            for (int rt = 0; rt < 2; ++rt)
                if (row[rt] < M)
#pragma unroll
                    for (int ct = 0; ct < 4; ++ct)
                        __builtin_nontemporal_store(acc[rt][ct],
                            reinterpret_cast<v4f*>(orow[rt] + ncol + 16 * ct + 4 * lg));
        }
    };

    // chunk loop over n, register double-buffered B fragments (nch is even: N=2048)
    const int nch = N >> 7;
    v8bf b0[4][2], b1[4][2];
    loadb(b0, 64 * wn);
#pragma unroll 1
    for (int i = 0; i < nch; i += 2) {
        loadb(b1, 128 * (i + 1) + 64 * wn);
        body(b0, 128 * i + 64 * wn);
        int nx = (i + 2 < nch) ? (i + 2) : (nch - 1);
        loadb(b0, 128 * nx + 64 * wn);
        body(b1, 128 * (i + 1) + 64 * wn);
    }
}

extern "C" void kernel_launch(void* const* d_in, const int* in_sizes, int n_in,
                              void* d_out, int out_size, void* d_ws, size_t ws_size,
                              hipStream_t stream) {
    const float* A = (const float*)d_in[0];
    const float* B = (const float*)d_in[1];
    const int M = in_sizes[0] / 64;   // 100000
    const int N = in_sizes[1] / 64;   // 2048

    unsigned short* Bbf = (unsigned short*)d_ws;                                   // N*64 bf16
    float* sq2 = (float*)((char*)d_ws + (size_t)N * 64 * sizeof(unsigned short));  // N f32
    float* out = (float*)d_out;

    prep_kernel<<<(N * 4 + 255) / 256, 256, 0, stream>>>(B, Bbf, sq2, N);

    const int gridM = (M + 63) / 64;
    dist_kernel<<<gridM, 256, 0, stream>>>(A, Bbf, sq2, out, M, N);
}

// Round 3
// 229.166 us; speedup vs baseline: 1.3839x; 1.3839x over previous
//
#include <hip/hip_runtime.h>
#include <cstdint>
#include <cstddef>

// dist[m][n] = ||a_m||^2 + ||b_n||^2 - 2 a_m.b_n ; M=100000, N=2048, K=64, f32.
// Cross term via bf16 MFMA 16x16x32, operands swapped (mfma(b, a)) so each
// lane's 4 acc elements are 4 consecutive output columns of one row.
// Round 3: 128-row blocks (halves Bbf HBM re-fetch), sq2 staged in LDS,
// single-buffered B frags, plain float4 stores.

typedef __bf16 v8bf __attribute__((ext_vector_type(8)));
typedef float  v4f  __attribute__((ext_vector_type(4)));

__device__ inline unsigned short f32_to_bf16_rne(float f) {
    union { float f; uint32_t u; } c; c.f = f;
    uint32_t u = c.u;
    uint32_t r = (u + 0x7fffu + ((u >> 16) & 1u)) >> 16;   // round-to-nearest-even
    return (unsigned short)r;
}

// mat_2 (N x 64 f32) -> Bbf = bf16(-2*b) in ws; sq2[n] = ||b_n||^2 (f32, exact).
__global__ __launch_bounds__(256) void prep_kernel(const float* __restrict__ B,
                                                   unsigned short* __restrict__ Bbf,
                                                   float* __restrict__ sq2, int N) {
    int t = blockIdx.x * 256 + threadIdx.x;   // 4 threads per row, 16 elems each
    int row = t >> 2;
    if (row >= N) return;
    int q = (t & 3) * 16;
    const float* src = B + (size_t)row * 64 + q;
    unsigned short* dst = Bbf + (size_t)row * 64 + q;
    float s = 0.f;
#pragma unroll
    for (int i = 0; i < 4; ++i) {
        float4 v = *reinterpret_cast<const float4*>(src + 4 * i);
        s += v.x * v.x + v.y * v.y + v.z * v.z + v.w * v.w;
        uint2 p;
        p.x = (uint32_t)f32_to_bf16_rne(-2.f * v.x) | ((uint32_t)f32_to_bf16_rne(-2.f * v.y) << 16);
        p.y = (uint32_t)f32_to_bf16_rne(-2.f * v.z) | ((uint32_t)f32_to_bf16_rne(-2.f * v.w) << 16);
        *reinterpret_cast<uint2*>(dst + 4 * i) = p;
    }
    s += __shfl_xor(s, 1);
    s += __shfl_xor(s, 2);
    if ((t & 3) == 0) sq2[row] = s;
}

// Block: 256 threads = 4 waves (2 row-halves x 2 col-halves). Block tile:
// 128 rows x N (chunks of 128 cols; each wave: 64 rows x 64 cols per chunk).
__global__ __launch_bounds__(256, 2) void dist_kernel(const float* __restrict__ A,
                                                      const unsigned short* __restrict__ Bbf,
                                                      const float* __restrict__ sq2,
                                                      float* __restrict__ out,
                                                      int M, int N) {
    __shared__ alignas(16) unsigned short a_lds[128][72];   // padded
    __shared__ float sq1_lds[128];
    __shared__ float sq2_lds[2048];

    const int t  = threadIdx.x;
    const int m0 = blockIdx.x * 128;

    // ---- stage sq2 into LDS (N = 2048, 8 f32/thread) ----
    {
        int base = t * 8;
        *reinterpret_cast<float4*>(&sq2_lds[base])     = *reinterpret_cast<const float4*>(&sq2[base]);
        *reinterpret_cast<float4*>(&sq2_lds[base + 4]) = *reinterpret_cast<const float4*>(&sq2[base + 4]);
    }

    // ---- stage A tile (f32 -> bf16) + row norms: 2 threads/row, 32 elems each ----
    {
        int r = t >> 1;
        int q = (t & 1) * 32;
        int m = m0 + r; if (m >= M) m = M - 1;   // clamp tail rows (stores predicated later)
        const float* src = A + (size_t)m * 64 + q;
        float s = 0.f;
#pragma unroll
        for (int i = 0; i < 8; ++i) {
            float4 v = *reinterpret_cast<const float4*>(src + 4 * i);
            s += v.x * v.x + v.y * v.y + v.z * v.z + v.w * v.w;
            uint2 p;
            p.x = (uint32_t)f32_to_bf16_rne(v.x) | ((uint32_t)f32_to_bf16_rne(v.y) << 16);
            p.y = (uint32_t)f32_to_bf16_rne(v.z) | ((uint32_t)f32_to_bf16_rne(v.w) << 16);
            *reinterpret_cast<uint2*>(&a_lds[r][q + 4 * i]) = p;
        }
        s += __shfl_xor(s, 1);
        if ((t & 1) == 0) sq1_lds[r] = s;
    }
    __syncthreads();

    const int lane = t & 63;
    const int w    = t >> 6;
    const int wm   = w >> 1;      // row half (64 rows each)
    const int wn   = w & 1;       // col half within 128-chunk
    const int lg   = lane >> 4;
    const int li   = lane & 15;

    // A fragments (MFMA 2nd operand): lane li = a-row-in-tile. Held all kernel.
    v8bf af[4][2];
#pragma unroll
    for (int rt = 0; rt < 4; ++rt)
#pragma unroll
        for (int kb = 0; kb < 2; ++kb)
            af[rt][kb] = *reinterpret_cast<const v8bf*>(&a_lds[64 * wm + 16 * rt + li][kb * 32 + 8 * lg]);

    float s1[4];
    int   row[4];
    float* orow[4];
#pragma unroll
    for (int rt = 0; rt < 4; ++rt) {
        row[rt]  = m0 + 64 * wm + 16 * rt + li;
        s1[rt]   = sq1_lds[64 * wm + 16 * rt + li];
        orow[rt] = out + (size_t)row[rt] * N;
    }
    const bool full = (m0 + 128 <= M);

#pragma unroll 1
    for (int nc = 0; nc < N; nc += 128) {
        const int ncol = nc + 64 * wn;

        // B fragments from global (bf16 in ws, L2-resident)
        v8bf bf[4][2];
#pragma unroll
        for (int ct = 0; ct < 4; ++ct)
#pragma unroll
            for (int kb = 0; kb < 2; ++kb)
                bf[ct][kb] = *reinterpret_cast<const v8bf*>(
                    &Bbf[(size_t)(ncol + 16 * ct + li) * 64 + kb * 32 + 8 * lg]);

        // sq2 from LDS (broadcast-friendly: 4 distinct addrs/instr)
        v4f s2v[4];
#pragma unroll
        for (int ct = 0; ct < 4; ++ct)
            s2v[ct] = *reinterpret_cast<const v4f*>(&sq2_lds[ncol + 16 * ct + 4 * lg]);

        v4f acc[4][4];
#pragma unroll
        for (int rt = 0; rt < 4; ++rt)
#pragma unroll
            for (int ct = 0; ct < 4; ++ct)
                acc[rt][ct] = s2v[ct] + s1[rt];

#pragma unroll
        for (int rt = 0; rt < 4; ++rt)
#pragma unroll
            for (int ct = 0; ct < 4; ++ct) {
                acc[rt][ct] = __builtin_amdgcn_mfma_f32_16x16x32_bf16(bf[ct][0], af[rt][0], acc[rt][ct], 0, 0, 0);
                acc[rt][ct] = __builtin_amdgcn_mfma_f32_16x16x32_bf16(bf[ct][1], af[rt][1], acc[rt][ct], 0, 0, 0);
            }

        // D mapping (swapped): lane li = a-row, regs j = 4 consecutive b-cols.
        if (full) {
#pragma unroll
            for (int rt = 0; rt < 4; ++rt)
#pragma unroll
                for (int ct = 0; ct < 4; ++ct)
                    *reinterpret_cast<v4f*>(orow[rt] + ncol + 16 * ct + 4 * lg) = acc[rt][ct];
        } else {
#pragma unroll
            for (int rt = 0; rt < 4; ++rt)
                if (row[rt] < M)
#pragma unroll
                    for (int ct = 0; ct < 4; ++ct)
                        *reinterpret_cast<v4f*>(orow[rt] + ncol + 16 * ct + 4 * lg) = acc[rt][ct];
        }
    }
}

extern "C" void kernel_launch(void* const* d_in, const int* in_sizes, int n_in,
                              void* d_out, int out_size, void* d_ws, size_t ws_size,
                              hipStream_t stream) {
    const float* A = (const float*)d_in[0];
    const float* B = (const float*)d_in[1];
    const int M = in_sizes[0] / 64;   // 100000
    const int N = in_sizes[1] / 64;   // 2048

    unsigned short* Bbf = (unsigned short*)d_ws;                                   // N*64 bf16
    float* sq2 = (float*)((char*)d_ws + (size_t)N * 64 * sizeof(unsigned short));  // N f32
    float* out = (float*)d_out;

    prep_kernel<<<(N * 4 + 255) / 256, 256, 0, stream>>>(B, Bbf, sq2, N);

    const int gridM = (M + 127) / 128;
    dist_kernel<<<gridM, 256, 0, stream>>>(A, Bbf, sq2, out, M, N);
}

// Round 4
// 200.641 us; speedup vs baseline: 1.5806x; 1.1422x over previous
//
#include <hip/hip_runtime.h>
#include <cstdint>
#include <cstddef>

// dist[m][n] = ||a_m||^2 + ||b_n||^2 - 2 a_m.b_n ; M=100000, N=2048, K=64, f32.
// Round 4: B pinned in LDS (128 KB half per block, XOR-swizzled), zero barriers
// in the main loop; A-frags loaded per-wave direct from global f32 (L1-shared).
// Cross term via bf16 MFMA 16x16x32 swapped (mfma(b,a)): lane li = a-row, the 4
// acc regs = 4 consecutive b-cols -> float4 stores. -2 folded into Bbf.

typedef __bf16 v8bf __attribute__((ext_vector_type(8)));
typedef float  v4f  __attribute__((ext_vector_type(4)));

__device__ inline unsigned short f32_to_bf16_rne(float f) {
    union { float f; uint32_t u; } c; c.f = f;
    uint32_t u = c.u;
    uint32_t r = (u + 0x7fffu + ((u >> 16) & 1u)) >> 16;   // round-to-nearest-even
    return (unsigned short)r;
}

// mat_2 (N x 64 f32) -> Bbf = bf16(-2*b) in ws; sq2[n] = ||b_n||^2 (f32, exact).
__global__ __launch_bounds__(256) void prep_kernel(const float* __restrict__ B,
                                                   unsigned short* __restrict__ Bbf,
                                                   float* __restrict__ sq2, int N) {
    int t = blockIdx.x * 256 + threadIdx.x;   // 4 threads per row, 16 elems each
    int row = t >> 2;
    if (row >= N) return;
    int q = (t & 3) * 16;
    const float* src = B + (size_t)row * 64 + q;
    unsigned short* dst = Bbf + (size_t)row * 64 + q;
    float s = 0.f;
#pragma unroll
    for (int i = 0; i < 4; ++i) {
        float4 v = *reinterpret_cast<const float4*>(src + 4 * i);
        s += v.x * v.x + v.y * v.y + v.z * v.z + v.w * v.w;
        uint2 p;
        p.x = (uint32_t)f32_to_bf16_rne(-2.f * v.x) | ((uint32_t)f32_to_bf16_rne(-2.f * v.y) << 16);
        p.y = (uint32_t)f32_to_bf16_rne(-2.f * v.z) | ((uint32_t)f32_to_bf16_rne(-2.f * v.w) << 16);
        *reinterpret_cast<uint2*>(dst + 4 * i) = p;
    }
    s += __shfl_xor(s, 1);
    s += __shfl_xor(s, 2);
    if ((t & 3) == 0) sq2[row] = s;
}

// Block: 512 threads = 8 waves, each wave owns a 64-col group. Block owns one
// 1024-col half of B (in LDS) and a strided set of 64-row A tiles.
__global__ __launch_bounds__(512, 1) void dist_kernel(const float* __restrict__ A,
                                                      const unsigned short* __restrict__ Bbf,
                                                      const float* __restrict__ sq2,
                                                      float* __restrict__ out,
                                                      int M, int N, int NT) {
    __shared__ __align__(16) unsigned char b_lds[131072];   // 1024 cols x 64 k x bf16

    const int t = threadIdx.x;
    const int h = blockIdx.x >> 8;     // half: 0/1
    const int s = blockIdx.x & 255;    // m-slice 0..255
    const int NH = N >> 1;             // 1024

    // ---- stage B half into LDS, XOR-swizzled: phys = L ^ ((col&7)<<4) ----
    {
        const unsigned short* src = Bbf + (size_t)h * NH * 64;
        const int nchunk = NH * 8;     // 16B chunks
        for (int idx = t; idx < nchunk; idx += 512) {
            int col = idx >> 3, q = idx & 7;
            uint4 v = *reinterpret_cast<const uint4*>(src + col * 64 + q * 8);
            int L = col * 128 + q * 16;
            *reinterpret_cast<uint4*>(b_lds + (L ^ ((col & 7) << 4))) = v;
        }
    }
    __syncthreads();   // only barrier in the kernel

    const int lane = t & 63;
    const int w    = t >> 6;        // col-group 0..7
    const int lg   = lane >> 4;
    const int li   = lane & 15;
    const int swz  = (li & 7) << 4; // read-side XOR (col&7 == li&7 here)

    // sq2 for this wave's columns (tile-invariant): col = h*NH + cc*512 + w*64 + 16ct + 4lg
    v4f s2v[2][4];
#pragma unroll
    for (int cc = 0; cc < 2; ++cc)
#pragma unroll
        for (int ct = 0; ct < 4; ++ct)
            s2v[cc][ct] = *reinterpret_cast<const v4f*>(
                &sq2[h * NH + cc * 512 + w * 64 + 16 * ct + 4 * lg]);

    // B fragments (tile-invariant!): hoist all 8 out of the tile loop
    v8bf bf[2][4][2];
#pragma unroll
    for (int cc = 0; cc < 2; ++cc)
#pragma unroll
        for (int ct = 0; ct < 4; ++ct)
#pragma unroll
            for (int kb = 0; kb < 2; ++kb) {
                int col = cc * 512 + w * 64 + 16 * ct + li;
                int L = col * 128 + kb * 64 + lg * 16;
                bf[cc][ct][kb] = *reinterpret_cast<const v8bf*>(b_lds + (L ^ swz));
            }

    // ---- tile loop: zero barriers ----
    for (int tt = s; tt < NT; tt += 256) {
        const int m0 = tt * 64;
        const bool full = (m0 + 64 <= M);

        // A fragments direct from global f32 (wave covers 64 rows x 64 k exactly once)
        v8bf  af[4][2];
        float s1[4];
#pragma unroll
        for (int rt = 0; rt < 4; ++rt) {
            int r = m0 + 16 * rt + li; if (r >= M) r = M - 1;
            const float* ar = A + (size_t)r * 64;
            float ss = 0.f;
#pragma unroll
            for (int kb = 0; kb < 2; ++kb) {
                float4 x0 = *reinterpret_cast<const float4*>(ar + kb * 32 + 8 * lg);
                float4 x1 = *reinterpret_cast<const float4*>(ar + kb * 32 + 8 * lg + 4);
                ss += x0.x * x0.x + x0.y * x0.y + x0.z * x0.z + x0.w * x0.w;
                ss += x1.x * x1.x + x1.y * x1.y + x1.z * x1.z + x1.w * x1.w;
                union { v8bf v; unsigned short u[8]; } pk;
                pk.u[0] = f32_to_bf16_rne(x0.x); pk.u[1] = f32_to_bf16_rne(x0.y);
                pk.u[2] = f32_to_bf16_rne(x0.z); pk.u[3] = f32_to_bf16_rne(x0.w);
                pk.u[4] = f32_to_bf16_rne(x1.x); pk.u[5] = f32_to_bf16_rne(x1.y);
                pk.u[6] = f32_to_bf16_rne(x1.z); pk.u[7] = f32_to_bf16_rne(x1.w);
                af[rt][kb] = pk.v;
            }
            ss += __shfl_xor(ss, 16);   // sum lg k-slices (lanes share li -> same row)
            ss += __shfl_xor(ss, 32);
            s1[rt] = ss;
        }

#pragma unroll
        for (int cc = 0; cc < 2; ++cc) {
            v4f acc[4][4];
#pragma unroll
            for (int rt = 0; rt < 4; ++rt)
#pragma unroll
                for (int ct = 0; ct < 4; ++ct)
                    acc[rt][ct] = s2v[cc][ct] + s1[rt];

#pragma unroll
            for (int rt = 0; rt < 4; ++rt)
#pragma unroll
                for (int ct = 0; ct < 4; ++ct) {
                    acc[rt][ct] = __builtin_amdgcn_mfma_f32_16x16x32_bf16(bf[cc][ct][0], af[rt][0], acc[rt][ct], 0, 0, 0);
                    acc[rt][ct] = __builtin_amdgcn_mfma_f32_16x16x32_bf16(bf[cc][ct][1], af[rt][1], acc[rt][ct], 0, 0, 0);
                }

            const int cbase = h * NH + cc * 512 + w * 64;
            if (full) {
#pragma unroll
                for (int rt = 0; rt < 4; ++rt) {
                    float* orow = out + (size_t)(m0 + 16 * rt + li) * N + cbase;
#pragma unroll
                    for (int ct = 0; ct < 4; ++ct)
                        *reinterpret_cast<v4f*>(orow + 16 * ct + 4 * lg) = acc[rt][ct];
                }
            } else {
#pragma unroll
                for (int rt = 0; rt < 4; ++rt) {
                    int r = m0 + 16 * rt + li;
                    if (r < M) {
                        float* orow = out + (size_t)r * N + cbase;
#pragma unroll
                        for (int ct = 0; ct < 4; ++ct)
                            *reinterpret_cast<v4f*>(orow + 16 * ct + 4 * lg) = acc[rt][ct];
                    }
                }
            }
        }
    }
}

extern "C" void kernel_launch(void* const* d_in, const int* in_sizes, int n_in,
                              void* d_out, int out_size, void* d_ws, size_t ws_size,
                              hipStream_t stream) {
    const float* A = (const float*)d_in[0];
    const float* B = (const float*)d_in[1];
    const int M = in_sizes[0] / 64;   // 100000
    const int N = in_sizes[1] / 64;   // 2048

    unsigned short* Bbf = (unsigned short*)d_ws;                                   // N*64 bf16
    float* sq2 = (float*)((char*)d_ws + (size_t)N * 64 * sizeof(unsigned short));  // N f32
    float* out = (float*)d_out;

    prep_kernel<<<(N * 4 + 255) / 256, 256, 0, stream>>>(B, Bbf, sq2, N);

    const int NT = (M + 63) / 64;   // 1563 row-tiles
    dist_kernel<<<512, 512, 0, stream>>>(A, Bbf, sq2, out, M, N, NT);
}

// Round 5
// 164.629 us; speedup vs baseline: 1.9264x; 1.2187x over previous
//
#include <hip/hip_runtime.h>
#include <cstdint>
#include <cstddef>

// dist[m][n] = ||a_m||^2 + ||b_n||^2 - 2 a_m.b_n ; M=100000, N=2048, K=64, f32.
// Round 5: B pinned in LDS (128 KB half/block, XOR-swizzled). 32-row tiles
// (M = 3125*32 exactly). A-loads for tile t+1 issued BEFORE tile t's stores
// (counted vmcnt, no store drain). Epilogue staged through per-wave 2 KB LDS
// so every global store instr writes full 128B lines (8 rows x 128 B), NT.

typedef __bf16 v8bf __attribute__((ext_vector_type(8)));
typedef float  v4f  __attribute__((ext_vector_type(4)));

__device__ inline unsigned short f32_to_bf16_rne(float f) {
    union { float f; uint32_t u; } c; c.f = f;
    uint32_t u = c.u;
    uint32_t r = (u + 0x7fffu + ((u >> 16) & 1u)) >> 16;   // round-to-nearest-even
    return (unsigned short)r;
}

// mat_2 (N x 64 f32) -> Bbf = bf16(-2*b) in ws; sq2[n] = ||b_n||^2 (f32, exact).
__global__ __launch_bounds__(256) void prep_kernel(const float* __restrict__ B,
                                                   unsigned short* __restrict__ Bbf,
                                                   float* __restrict__ sq2, int N) {
    int t = blockIdx.x * 256 + threadIdx.x;   // 4 threads per row, 16 elems each
    int row = t >> 2;
    if (row >= N) return;
    int q = (t & 3) * 16;
    const float* src = B + (size_t)row * 64 + q;
    unsigned short* dst = Bbf + (size_t)row * 64 + q;
    float s = 0.f;
#pragma unroll
    for (int i = 0; i < 4; ++i) {
        float4 v = *reinterpret_cast<const float4*>(src + 4 * i);
        s += v.x * v.x + v.y * v.y + v.z * v.z + v.w * v.w;
        uint2 p;
        p.x = (uint32_t)f32_to_bf16_rne(-2.f * v.x) | ((uint32_t)f32_to_bf16_rne(-2.f * v.y) << 16);
        p.y = (uint32_t)f32_to_bf16_rne(-2.f * v.z) | ((uint32_t)f32_to_bf16_rne(-2.f * v.w) << 16);
        *reinterpret_cast<uint2*>(dst + 4 * i) = p;
    }
    s += __shfl_xor(s, 1);
    s += __shfl_xor(s, 2);
    if ((t & 3) == 0) sq2[row] = s;
}

// 512 threads = 8 waves; block owns one 1024-col half of B (LDS) and a strided
// set of 32-row A tiles. Wave w owns a 64-col group (x2 via cc loop).
__global__ __launch_bounds__(512, 1) void dist_kernel(const float* __restrict__ A,
                                                      const unsigned short* __restrict__ Bbf,
                                                      const float* __restrict__ sq2,
                                                      float* __restrict__ out,
                                                      int M, int N, int NT) {
    __shared__ __align__(16) unsigned char b_lds[131072];   // 1024 cols x 64 k x bf16
    __shared__ __align__(16) float stage_lds[8][512];       // 2 KB per wave

    const int t = threadIdx.x;
    const int h = blockIdx.x >> 8;     // half: 0/1
    const int s = blockIdx.x & 255;    // m-slice 0..255
    const int NH = N >> 1;             // 1024

    // ---- stage B half into LDS, XOR-swizzled: phys = L ^ ((col&7)<<4) ----
    {
        const unsigned short* src = Bbf + (size_t)h * NH * 64;
        const int nchunk = NH * 8;     // 16B chunks
        for (int idx = t; idx < nchunk; idx += 512) {
            int col = idx >> 3, q = idx & 7;
            uint4 v = *reinterpret_cast<const uint4*>(src + col * 64 + q * 8);
            int L = col * 128 + q * 16;
            *reinterpret_cast<uint4*>(b_lds + (L ^ ((col & 7) << 4))) = v;
        }
    }
    __syncthreads();   // only barrier in the kernel

    const int lane = t & 63;
    const int w    = t >> 6;        // col-group 0..7
    const int lg   = lane >> 4;
    const int li   = lane & 15;
    const int swz  = (li & 7) << 4;
    float* const stg = &stage_lds[w][0];

    // sq2 for this wave's columns (tile-invariant)
    v4f s2v[2][4];
#pragma unroll
    for (int cc = 0; cc < 2; ++cc)
#pragma unroll
        for (int ct = 0; ct < 4; ++ct)
            s2v[cc][ct] = *reinterpret_cast<const v4f*>(
                &sq2[h * NH + cc * 512 + w * 64 + 16 * ct + 4 * lg]);

    // B fragments (tile-invariant): hoisted for the whole kernel
    v8bf bf[2][4][2];
#pragma unroll
    for (int cc = 0; cc < 2; ++cc)
#pragma unroll
        for (int ct = 0; ct < 4; ++ct)
#pragma unroll
            for (int kb = 0; kb < 2; ++kb) {
                int col = cc * 512 + w * 64 + 16 * ct + li;
                int L = col * 128 + kb * 64 + lg * 16;
                bf[cc][ct][kb] = *reinterpret_cast<const v8bf*>(b_lds + (L ^ swz));
            }

    // raw A prefetch registers: [rt][kb][pair] -> 8 float4
    float4 raw[8];
    auto loadA = [&](int tt) {
        const int m0 = tt * 32;
#pragma unroll
        for (int rt = 0; rt < 2; ++rt) {
            int r = m0 + 16 * rt + li; if (r >= M) r = M - 1;
            const float* ar = A + (size_t)r * 64;
#pragma unroll
            for (int kb = 0; kb < 2; ++kb) {
                raw[rt * 4 + kb * 2]     = *reinterpret_cast<const float4*>(ar + kb * 32 + 8 * lg);
                raw[rt * 4 + kb * 2 + 1] = *reinterpret_cast<const float4*>(ar + kb * 32 + 8 * lg + 4);
            }
        }
    };

    loadA(s);   // prologue prefetch

#pragma unroll 1
    for (int tt = s; tt < NT; tt += 256) {
        const int m0 = tt * 32;

        // ---- convert raw -> af, row norms ----
        v8bf  af[2][2];
        float s1[2];
#pragma unroll
        for (int rt = 0; rt < 2; ++rt) {
            float ss = 0.f;
#pragma unroll
            for (int kb = 0; kb < 2; ++kb) {
                float4 x0 = raw[rt * 4 + kb * 2];
                float4 x1 = raw[rt * 4 + kb * 2 + 1];
                ss += x0.x * x0.x + x0.y * x0.y + x0.z * x0.z + x0.w * x0.w;
                ss += x1.x * x1.x + x1.y * x1.y + x1.z * x1.z + x1.w * x1.w;
                union { v8bf v; unsigned short u[8]; } pk;
                pk.u[0] = f32_to_bf16_rne(x0.x); pk.u[1] = f32_to_bf16_rne(x0.y);
                pk.u[2] = f32_to_bf16_rne(x0.z); pk.u[3] = f32_to_bf16_rne(x0.w);
                pk.u[4] = f32_to_bf16_rne(x1.x); pk.u[5] = f32_to_bf16_rne(x1.y);
                pk.u[6] = f32_to_bf16_rne(x1.z); pk.u[7] = f32_to_bf16_rne(x1.w);
                af[rt][kb] = pk.v;
            }
            ss += __shfl_xor(ss, 16);   // sum k-slices across lg (same row li)
            ss += __shfl_xor(ss, 32);
            s1[rt] = ss;
        }

        // ---- issue next tile's A loads BEFORE this tile's stores ----
        {
            int tn = tt + 256; if (tn >= NT) tn = tt;
            loadA(tn);
        }

#pragma unroll
        for (int cc = 0; cc < 2; ++cc) {
            v4f acc[2][4];
#pragma unroll
            for (int rt = 0; rt < 2; ++rt)
#pragma unroll
                for (int ct = 0; ct < 4; ++ct)
                    acc[rt][ct] = s2v[cc][ct] + s1[rt];

#pragma unroll
            for (int rt = 0; rt < 2; ++rt)
#pragma unroll
                for (int ct = 0; ct < 4; ++ct) {
                    acc[rt][ct] = __builtin_amdgcn_mfma_f32_16x16x32_bf16(bf[cc][ct][0], af[rt][0], acc[rt][ct], 0, 0, 0);
                    acc[rt][ct] = __builtin_amdgcn_mfma_f32_16x16x32_bf16(bf[cc][ct][1], af[rt][1], acc[rt][ct], 0, 0, 0);
                }

            const int cbase = h * NH + cc * 512 + w * 64;
            // ---- LDS-staged epilogue: full-line (128B) nontemporal stores ----
#pragma unroll
            for (int rt = 0; rt < 2; ++rt) {
#pragma unroll
                for (int hf = 0; hf < 2; ++hf) {
                    // write 16 rows x 32 cols slice (cols 32*hf..+32), XOR-swizzled
#pragma unroll
                    for (int q = 0; q < 2; ++q) {
                        int c = 16 * q + 4 * lg;                 // float col in [0,32)
                        *reinterpret_cast<v4f*>(&stg[li * 32 + (c ^ (4 * (li & 7)))]) =
                            acc[rt][2 * hf + q];
                    }
                    // read back coalesced: 8 rows x 128B per store instr
#pragma unroll
                    for (int g = 0; g < 2; ++g) {
                        int r2 = 8 * g + (lane >> 3);            // row in [0,16)
                        int c2 = 4 * (lane & 7);                 // float col in [0,32)
                        v4f v = *reinterpret_cast<const v4f*>(
                            &stg[r2 * 32 + (c2 ^ (4 * (r2 & 7)))]);
                        int grow = m0 + 16 * rt + r2;
                        if (grow < M)
                            __builtin_nontemporal_store(v,
                                reinterpret_cast<v4f*>(out + (size_t)grow * N + cbase + 32 * hf + c2));
                    }
                }
            }
        }
    }
}

extern "C" void kernel_launch(void* const* d_in, const int* in_sizes, int n_in,
                              void* d_out, int out_size, void* d_ws, size_t ws_size,
                              hipStream_t stream) {
    const float* A = (const float*)d_in[0];
    const float* B = (const float*)d_in[1];
    const int M = in_sizes[0] / 64;   // 100000
    const int N = in_sizes[1] / 64;   // 2048

    unsigned short* Bbf = (unsigned short*)d_ws;                                   // N*64 bf16
    float* sq2 = (float*)((char*)d_ws + (size_t)N * 64 * sizeof(unsigned short));  // N f32
    float* out = (float*)d_out;

    prep_kernel<<<(N * 4 + 255) / 256, 256, 0, stream>>>(B, Bbf, sq2, N);

    const int NT = (M + 31) / 32;   // 3125 row-tiles (exact: M = 3125*32)
    dist_kernel<<<512, 512, 0, stream>>>(A, Bbf, sq2, out, M, N, NT);
}

// Round 6
// 164.497 us; speedup vs baseline: 1.9279x; 1.0008x over previous
//
#include <hip/hip_runtime.h>
#include <cstdint>
#include <cstddef>

// dist[m][n] = ||a_m||^2 + ||b_n||^2 - 2 a_m.b_n ; M=100000 (=3125*32), N=2048, K=64, f32.
// Round 6: SINGLE kernel. Each block stages its 1024-col B-half directly from
// f32 (convert to bf16(-2b), XOR-swizzled LDS) and computes sq2 in f32 via
// shfl reduction -> no prep kernel, no ws round-trip. 32-row A tiles with
// next-tile loads issued BEFORE current stores (counted vmcnt). Epilogue staged
// through per-wave 2 KB LDS so every global store writes full 128B lines, NT.

typedef __bf16 v8bf __attribute__((ext_vector_type(8)));
typedef float  v4f  __attribute__((ext_vector_type(4)));

__device__ inline unsigned short f32_to_bf16_rne(float f) {
    union { float f; uint32_t u; } c; c.f = f;
    uint32_t u = c.u;
    uint32_t r = (u + 0x7fffu + ((u >> 16) & 1u)) >> 16;   // round-to-nearest-even
    return (unsigned short)r;
}
__device__ inline uint32_t pack2_m2(float a, float b) {    // bf16(-2a) | bf16(-2b)<<16
    return (uint32_t)f32_to_bf16_rne(-2.f * a) | ((uint32_t)f32_to_bf16_rne(-2.f * b) << 16);
}

// 512 threads = 8 waves; block owns one 1024-col half of B (LDS) and a strided
// set of 32-row A tiles. Wave w owns a 64-col group (x2 via cc loop).
__global__ __launch_bounds__(512, 1) void dist_kernel(const float* __restrict__ A,
                                                      const float* __restrict__ B,
                                                      float* __restrict__ out,
                                                      int M, int N, int NT) {
    __shared__ __align__(16) unsigned char b_lds[131072];   // 1024 cols x 64 k x bf16
    __shared__ __align__(16) float stage_lds[8][512];       // 2 KB per wave
    __shared__ float sq2_lds[1024];

    const int t = threadIdx.x;
    const int h = blockIdx.x >> 8;     // half: 0/1
    const int s = blockIdx.x & 255;    // m-slice 0..255
    const int NH = N >> 1;             // 1024

    const int lane = t & 63;
    const int w    = t >> 6;        // col-group 0..7
    const int lg   = lane >> 4;
    const int li   = lane & 15;
    const int swz  = (li & 7) << 4;
    float* const stg = &stage_lds[w][0];

    // raw A prefetch registers: [rt][kb][pair] -> 8 float4
    float4 raw[8];
    auto loadA = [&](int tt) {
        const int m0 = tt * 32;
#pragma unroll
        for (int rt = 0; rt < 2; ++rt) {
            const float* ar = A + (size_t)(m0 + 16 * rt + li) * 64;
#pragma unroll
            for (int kb = 0; kb < 2; ++kb) {
                raw[rt * 4 + kb * 2]     = *reinterpret_cast<const float4*>(ar + kb * 32 + 8 * lg);
                raw[rt * 4 + kb * 2 + 1] = *reinterpret_cast<const float4*>(ar + kb * 32 + 8 * lg + 4);
            }
        }
    };
    loadA(s);   // issue first tile's A loads before B staging (overlap)

    // ---- stage B half f32 -> bf16(-2b), XOR-swizzled; sq2 exact f32 ----
    {
        const float* src = B + (size_t)h * NH * 64;
        const int nchunk = NH * 8;     // 16B-bf16 chunks (8 values each)
#pragma unroll 1
        for (int idx = t; idx < nchunk; idx += 512) {
            int col = idx >> 3, q = idx & 7;
            float4 x0 = *reinterpret_cast<const float4*>(src + col * 64 + q * 8);
            float4 x1 = *reinterpret_cast<const float4*>(src + col * 64 + q * 8 + 4);
            float ss = x0.x * x0.x + x0.y * x0.y + x0.z * x0.z + x0.w * x0.w
                     + x1.x * x1.x + x1.y * x1.y + x1.z * x1.z + x1.w * x1.w;
            uint4 v;
            v.x = pack2_m2(x0.x, x0.y); v.y = pack2_m2(x0.z, x0.w);
            v.z = pack2_m2(x1.x, x1.y); v.w = pack2_m2(x1.z, x1.w);
            int L = col * 128 + q * 16;
            *reinterpret_cast<uint4*>(b_lds + (L ^ ((col & 7) << 4))) = v;
            ss += __shfl_xor(ss, 1);    // reduce the 8 q-chunks of this col
            ss += __shfl_xor(ss, 2);
            ss += __shfl_xor(ss, 4);
            if ((t & 7) == 0) sq2_lds[col] = ss;
        }
    }
    __syncthreads();   // only barrier in the kernel

    // sq2 for this wave's columns (tile-invariant), from LDS
    v4f s2v[2][4];
#pragma unroll
    for (int cc = 0; cc < 2; ++cc)
#pragma unroll
        for (int ct = 0; ct < 4; ++ct)
            s2v[cc][ct] = *reinterpret_cast<const v4f*>(
                &sq2_lds[cc * 512 + w * 64 + 16 * ct + 4 * lg]);

    // B fragments (tile-invariant): hoisted for the whole kernel
    v8bf bf[2][4][2];
#pragma unroll
    for (int cc = 0; cc < 2; ++cc)
#pragma unroll
        for (int ct = 0; ct < 4; ++ct)
#pragma unroll
            for (int kb = 0; kb < 2; ++kb) {
                int col = cc * 512 + w * 64 + 16 * ct + li;
                int L = col * 128 + kb * 64 + lg * 16;
                bf[cc][ct][kb] = *reinterpret_cast<const v8bf*>(b_lds + (L ^ swz));
            }

#pragma unroll 1
    for (int tt = s; tt < NT; tt += 256) {
        const int m0 = tt * 32;

        // ---- convert raw -> af, row norms ----
        v8bf  af[2][2];
        float s1[2];
#pragma unroll
        for (int rt = 0; rt < 2; ++rt) {
            float ss = 0.f;
#pragma unroll
            for (int kb = 0; kb < 2; ++kb) {
                float4 x0 = raw[rt * 4 + kb * 2];
                float4 x1 = raw[rt * 4 + kb * 2 + 1];
                ss += x0.x * x0.x + x0.y * x0.y + x0.z * x0.z + x0.w * x0.w;
                ss += x1.x * x1.x + x1.y * x1.y + x1.z * x1.z + x1.w * x1.w;
                union { v8bf v; unsigned short u[8]; } pk;
                pk.u[0] = f32_to_bf16_rne(x0.x); pk.u[1] = f32_to_bf16_rne(x0.y);
                pk.u[2] = f32_to_bf16_rne(x0.z); pk.u[3] = f32_to_bf16_rne(x0.w);
                pk.u[4] = f32_to_bf16_rne(x1.x); pk.u[5] = f32_to_bf16_rne(x1.y);
                pk.u[6] = f32_to_bf16_rne(x1.z); pk.u[7] = f32_to_bf16_rne(x1.w);
                af[rt][kb] = pk.v;
            }
            ss += __shfl_xor(ss, 16);   // sum k-slices across lg (same row li)
            ss += __shfl_xor(ss, 32);
            s1[rt] = ss;
        }

        // ---- issue next tile's A loads BEFORE this tile's stores ----
        {
            int tn = tt + 256; if (tn >= NT) tn = tt;
            loadA(tn);
        }

#pragma unroll
        for (int cc = 0; cc < 2; ++cc) {
            v4f acc[2][4];
#pragma unroll
            for (int rt = 0; rt < 2; ++rt)
#pragma unroll
                for (int ct = 0; ct < 4; ++ct)
                    acc[rt][ct] = s2v[cc][ct] + s1[rt];

#pragma unroll
            for (int rt = 0; rt < 2; ++rt)
#pragma unroll
                for (int ct = 0; ct < 4; ++ct) {
                    acc[rt][ct] = __builtin_amdgcn_mfma_f32_16x16x32_bf16(bf[cc][ct][0], af[rt][0], acc[rt][ct], 0, 0, 0);
                    acc[rt][ct] = __builtin_amdgcn_mfma_f32_16x16x32_bf16(bf[cc][ct][1], af[rt][1], acc[rt][ct], 0, 0, 0);
                }

            const int cbase = h * NH + cc * 512 + w * 64;
            // ---- LDS-staged epilogue: full-line (128B) nontemporal stores ----
#pragma unroll
            for (int rt = 0; rt < 2; ++rt) {
#pragma unroll
                for (int hf = 0; hf < 2; ++hf) {
#pragma unroll
                    for (int q = 0; q < 2; ++q) {
                        int c = 16 * q + 4 * lg;                 // float col in [0,32)
                        *reinterpret_cast<v4f*>(&stg[li * 32 + (c ^ (4 * (li & 7)))]) =
                            acc[rt][2 * hf + q];
                    }
#pragma unroll
                    for (int g = 0; g < 2; ++g) {
                        int r2 = 8 * g + (lane >> 3);            // row in [0,16)
                        int c2 = 4 * (lane & 7);                 // float col in [0,32)
                        v4f v = *reinterpret_cast<const v4f*>(
                            &stg[r2 * 32 + (c2 ^ (4 * (r2 & 7)))]);
                        __builtin_nontemporal_store(v,
                            reinterpret_cast<v4f*>(out + (size_t)(m0 + 16 * rt + r2) * N
                                                   + cbase + 32 * hf + c2));
                    }
                }
            }
        }
    }
}

extern "C" void kernel_launch(void* const* d_in, const int* in_sizes, int n_in,
                              void* d_out, int out_size, void* d_ws, size_t ws_size,
                              hipStream_t stream) {
    const float* A = (const float*)d_in[0];
    const float* B = (const float*)d_in[1];
    const int M = in_sizes[0] / 64;   // 100000 = 3125*32
    const int N = in_sizes[1] / 64;   // 2048
    float* out = (float*)d_out;

    const int NT = (M + 31) / 32;     // 3125 row-tiles, exact
    dist_kernel<<<512, 512, 0, stream>>>(A, B, out, M, N, NT);
}